// Round 9
// baseline (80.784 us; speedup 1.0000x reference)
//
#include <hip/hip_runtime.h>
#include <math.h>

#define NMAX   64
#define NSITES 12
#define BLOCK  256
#define EPB    64     // elements per block: one per lane; wave w owns sites 3w..3w+2
#define RS     68     // neighbor row stride (floats); rows 16B-aligned

#define B_SOFT 0.01f
#define PAD_C  14.0f  // sentinel coord: r2 in [~200,~650] -> f ~ 6e-8, inside table
#define TBL_LO 1392   // (bits >> 19) of 2^-40
#define TBL_N  800    // 16 bins/octave lerp, r2 in [2^-40, 2^10); covers sentinels
#define RAW_LO (TBL_LO * 8)           // 11136: table byte offset in LDS; the
                                      // gather vaddr is (bits>>16)&~7 with NO
                                      // bias add (r2>=2^-40 -> raw>=RAW_LO)

#define NB_F   (NSITES * RS)          // 816 floats per coord array
#define EPSF   9.094947e-13f          // 2^-40, folded into the r2 fma

// Device-global: f32 (c,s) lerp table + compacted SoA neighbors.  Neighbors
// are read in the main loop with wave-uniform addresses -> scalar s_load
// (constant cache), off both the LDS and VMEM-gather paths.
__device__ __align__(16) float2 g_tbl[TBL_N];
__device__ __align__(16) float  g_nb[2 * NB_F];

// LDS: partials [0,768B) | unused | table [RAW_LO, RAW_LO+6400)
#define SMEM_F ((RAW_LO + TBL_N * 8) / 4)   // 17536 B -> 8 blocks/CU

// f(r2) = exp(-sqrt(r2)) / (sqrt(r2) + b), exact (init kernel only)
__device__ __forceinline__ float f_exact(float r2) {
    const float r = sqrtf(r2);
    return expf(-r) / (r + B_SOFT);
}

// One block, once per launch: build lerp table + ballot-compact neighbors.
__global__ void init_kernel(const float* __restrict__ neighbors,
                            const float* __restrict__ mask) {
    const int tid  = threadIdx.x;
    const int wv   = tid >> 6;
    const int lane = tid & 63;

    // Piecewise-linear table: bin i covers r2-bits [ (i+LO)<<19, (i+LO+1)<<19 );
    // chord + midpoint correction halves the max lerp error.
    for (int i = tid; i < TBL_N; i += BLOCK) {
        const unsigned ii = (unsigned)(i + TBL_LO);
        const float b0 = __builtin_bit_cast(float, ii << 19);
        const float b1 = __builtin_bit_cast(float, (ii + 1u) << 19);
        const float f0 = f_exact(b0);
        const float f1 = f_exact(b1);
        const float fm = f_exact(0.5f * (b0 + b1));
        const float sl = (f1 - f0) / (b1 - b0);
        const float c  = f0 - sl * b0 - 0.5f * (0.5f * (f0 + f1) - fm);
        g_tbl[i] = make_float2(c, sl);
    }

    // Sentinel fill: all 64 j-slots are always processed; slots past a
    // site's real count give r2 in [200,650] -> f ~ 6e-8 each (negligible).
    for (int i = tid; i < 2 * NB_F; i += BLOCK) g_nb[i] = PAD_C;
    __syncthreads();

    for (int s = wv; s < NSITES; s += 4) {
        const bool keep = mask[s * NMAX + lane] > 0.5f;
        const unsigned long long bal = __ballot(keep);
        if (keep) {
            const int pos = __popcll(bal & ((1ull << lane) - 1ull));
            const float2 p = ((const float2*)neighbors)[s * NMAX + lane];
            g_nb[s * RS + pos]        = p.x;
            g_nb[NB_F + s * RS + pos] = p.y;
        }
    }
}

__global__ __launch_bounds__(BLOCK, 8)
void pot_energy_kernel(const float* __restrict__ x,
                       float* __restrict__ out, int B) {
    __shared__ __align__(16) float smem[SMEM_F];
    const int tid  = threadIdx.x;
    const int w    = tid >> 6;     // wave = site-quadrant (uniform per wave)
    const int lane = tid & 63;     // lane = element within the block

    // Prologue: copy the table into LDS at byte offset RAW_LO.
    {
        const float4* s4 = (const float4*)g_tbl;       // 400 float4
        float4* d4 = (float4*)((char*)smem + RAW_LO);
        #pragma unroll
        for (int i0 = 0; i0 < 2; ++i0) {
            const int i = tid + i0 * BLOCK;
            if (i < (TBL_N * 8) / 16) d4[i] = s4[i];
        }
    }
    const int q = __builtin_amdgcn_readfirstlane(w);
    __syncthreads();

    const int e  = blockIdx.x * EPB + lane;
    const int el = (e < B) ? e : 0;

    // This wave's 3 site positions for element e: 6 contiguous floats.
    const float* xb = x + (size_t)el * 24 + q * 6;
    const float2 pa = ((const float2*)xb)[0];
    const float2 pb = ((const float2*)xb)[1];
    const float2 pc = ((const float2*)xb)[2];
    const float xs_[3] = { pa.x, pb.x, pc.x };
    const float ys_[3] = { pa.y, pb.y, pc.y };

    float accC0 = 0.f, accC1 = 0.f, accS0 = 0.f, accS1 = 0.f;
    #pragma unroll
    for (int s = 0; s < 3; ++s) {
        const int site = q * 3 + s;
        // Wave-uniform addresses -> scalar loads into SGPRs; used directly
        // as VALU operands (no LDS, no VMEM on the neighbor path).
        const float* __restrict__ rx = g_nb + site * RS;
        const float* __restrict__ ry = rx + NB_F;
        const float xs = xs_[s];
        const float ys = ys_[s];
        // 4 statically-unrolled groups of 16: compute 16 r2's, then issue 16
        // gathers back-to-back (4x deeper LDS pipelining than chunk-of-4),
        // then 16 consumes.  All j-indices compile-time -> registers.
        #pragma unroll
        for (int j0 = 0; j0 < 64; j0 += 16) {
            float r2v[16];
            #pragma unroll
            for (int jj = 0; jj < 16; ++jj) {
                const float dx = xs - rx[j0 + jj];
                const float dy = ys - ry[j0 + jj];
                r2v[jj] = fmaf(dy, dy, fmaf(dx, dx, EPSF));
            }
            #pragma unroll
            for (int jj = 0; jj < 16; ++jj) {
                // table overlay: vaddr = (bits>>16)&~7, zero bias ops
                const unsigned raw =
                    (__builtin_bit_cast(unsigned, r2v[jj]) >> 16) & 0xFFF8u;
                const float2 cs = *(const float2*)((const char*)smem + raw);
                if (jj & 1) { accC1 += cs.x; accS1 = fmaf(cs.y, r2v[jj], accS1); }
                else        { accC0 += cs.x; accS0 = fmaf(cs.y, r2v[jj], accS0); }
            }
        }
    }

    // Combine the 4 wave-partials of each element via LDS (bytes [0,768)).
    const float av = (accC0 + accC1) + (accS0 + accS1);
    if (w != 0) smem[(w - 1) * EPB + lane] = av;
    __syncthreads();
    if (w == 0 && e < B) {
        out[e] = av + smem[lane]
                    + smem[EPB + lane]
                    + smem[2 * EPB + lane];   // coalesced store
    }
}

extern "C" void kernel_launch(void* const* d_in, const int* in_sizes, int n_in,
                              void* d_out, int out_size, void* d_ws, size_t ws_size,
                              hipStream_t stream) {
    const float* x   = (const float*)d_in[0];
    const float* nbr = (const float*)d_in[1];
    const float* msk = (const float*)d_in[2];
    float* out = (float*)d_out;

    const int B = in_sizes[0] / 24;

    init_kernel<<<1, BLOCK, 0, stream>>>(nbr, msk);

    const int blocks = (B + EPB - 1) / EPB;
    pot_energy_kernel<<<blocks, BLOCK, 0, stream>>>(x, out, B);
}

// Round 10
// 80.411 us; speedup vs baseline: 1.0046x; 1.0046x over previous
//
#include <hip/hip_runtime.h>
#include <math.h>

#define NMAX   64
#define NSITES 12
#define BLOCK  256
#define EPB    64     // elements per block: one per lane; wave w owns sites 3w..3w+2
#define RS     68     // neighbor row stride (floats); rows 16B-aligned

#define B_SOFT 0.01f
#define PAD_C  14.0f  // sentinel coord: r2 in [~155,~740] -> f ~ 3e-7, inside table
#define TBL_LO 1392   // (bits>>19) of 2^-40
#define TBL_N  800    // 16 bins/octave lerp, r2 in [2^-40, 2^10); real r2 <= ~250
#define RAW_LO (TBL_LO * 8)   // 11136 = low bound of (bits>>16)&~7

#define NB_F   (NSITES * RS)          // 816 floats per coord array

// Device-global: f32 (c,s) lerp table + compacted SoA neighbors.
// Neighbors are read DIRECTLY from here in the main loop with wave-uniform
// addresses -> scalar loads (s_load_dwordx4 via constant cache), taking the
// 2x ds_read_b128/chunk OFF the CU-shared LDS pipe.  LDS carries only the
// random table gather.  (R8 structure: measured best, 79.37 us.)
__device__ __align__(16) float2 g_tbl[TBL_N];
__device__ __align__(16) float  g_nb[2 * NB_F];
__device__ int g_mq[4];

// LDS float layout: table [0,1600) | partials [1600,1792)
#define L_PART (2 * TBL_N)
#define SMEM_F (L_PART + 3 * EPB)     // 1792 floats = 7168 B -> 8 blocks/CU

typedef float v2f __attribute__((ext_vector_type(2)));
typedef float v4f __attribute__((ext_vector_type(4)));

// f(r2) = exp(-sqrt(r2)) / (sqrt(r2) + b), exact (init kernel only)
__device__ __forceinline__ float f_exact(float r2) {
    const float r = sqrtf(r2);
    return expf(-r) / (r + B_SOFT);
}

// One block, once per launch: build lerp table + ballot-compact neighbors.
__global__ void init_kernel(const float* __restrict__ neighbors,
                            const float* __restrict__ mask) {
    __shared__ int cnt[NSITES];
    const int tid  = threadIdx.x;
    const int wv   = tid >> 6;
    const int lane = tid & 63;

    // Piecewise-linear table: bin i covers r2-bits [ (i+LO)<<19, (i+LO+1)<<19 );
    // chord + midpoint correction halves the max lerp error.
    for (int i = tid; i < TBL_N; i += BLOCK) {
        const unsigned ii = (unsigned)(i + TBL_LO);
        const float b0 = __builtin_bit_cast(float, ii << 19);
        const float b1 = __builtin_bit_cast(float, (ii + 1u) << 19);
        const float f0 = f_exact(b0);
        const float f1 = f_exact(b1);
        const float fm = f_exact(0.5f * (b0 + b1));
        const float sl = (f1 - f0) / (b1 - b0);
        const float c  = f0 - sl * b0 - 0.5f * (0.5f * (f0 + f1) - fm);
        g_tbl[i] = make_float2(c, sl);
    }

    // Sentinel fill: slots past a site's count -> r2 in [155,740] -> f~3e-7.
    for (int i = tid; i < 2 * NB_F; i += BLOCK) g_nb[i] = PAD_C;
    __syncthreads();

    for (int s = wv; s < NSITES; s += 4) {
        const bool keep = mask[s * NMAX + lane] > 0.5f;
        const unsigned long long bal = __ballot(keep);
        if (keep) {
            const int pos = __popcll(bal & ((1ull << lane) - 1ull));
            const float2 p = ((const float2*)neighbors)[s * NMAX + lane];
            g_nb[s * RS + pos]        = p.x;
            g_nb[NB_F + s * RS + pos] = p.y;
        }
        if (lane == 0) cnt[s] = __popcll(bal);
    }
    __syncthreads();
    if (tid < 4) {    // per-wave loop bound: max over that wave's 3 sites
        const int mm = max(cnt[3 * tid],
                       max(cnt[3 * tid + 1], cnt[3 * tid + 2]));
        g_mq[tid] = (mm + 3) & ~3;   // <= 64, RS-safe
    }
}

__global__ __launch_bounds__(BLOCK, 8)
void pot_energy_kernel(const float* __restrict__ x,
                       float* __restrict__ out, int B) {
    __shared__ __align__(16) float smem[SMEM_F];
    const int tid  = threadIdx.x;
    const int w    = tid >> 6;     // wave = site-quadrant (uniform per wave)
    const int lane = tid & 63;     // lane = element within the block

    // Prologue: copy ONLY the table into LDS (6.4 KB).
    {
        const float4* s4 = (const float4*)g_tbl;   // 800 float2 = 400 f4
        float4* d4 = (float4*)smem;
        #pragma unroll
        for (int i0 = 0; i0 < 2; ++i0) {
            const int i = tid + i0 * BLOCK;
            if (i < (2 * TBL_N) / 4) d4[i] = s4[i];
        }
    }
    const int q = __builtin_amdgcn_readfirstlane(w);
    const int m = g_mq[q];         // wave-uniform -> scalar load
    __syncthreads();

    const int e  = blockIdx.x * EPB + lane;
    const int el = (e < B) ? e : 0;

    // This wave's 3 site positions for element e: 6 contiguous floats.
    const float* xb = x + (size_t)el * 24 + q * 6;
    const float2 pa = ((const float2*)xb)[0];
    const float2 pb = ((const float2*)xb)[1];
    const float2 pc = ((const float2*)xb)[2];
    const float xs_[3] = { pa.x, pb.x, pc.x };
    const float ys_[3] = { pa.y, pb.y, pc.y };

    const char* tb = (const char*)smem - RAW_LO;   // tb + raw indexes table
    const v2f eps2 = { 9.094947e-13f, 9.094947e-13f };   // 2^-40 floor, in-fma

    float accC = 0.f, accS = 0.f;   // sum(c_i) and sum(s_i * r2_i)
    #pragma unroll
    for (int s = 0; s < 3; ++s) {
        const int site = q * 3 + s;
        // Wave-uniform global addresses -> scalar (SMEM) loads through the
        // constant cache: NOT on the LDS pipe, NOT on the VMEM gather path.
        const float* __restrict__ rx = g_nb + site * RS;
        const float* __restrict__ ry = rx + NB_F;
        const v2f xs2 = { xs_[s], xs_[s] };
        const v2f ys2 = { ys_[s], ys_[s] };
        #pragma unroll 2
        for (int j0 = 0; j0 < m; j0 += 4) {
            const v4f nx4 = *(const v4f*)(rx + j0);   // s_load_dwordx4
            const v4f ny4 = *(const v4f*)(ry + j0);   // s_load_dwordx4
            const v2f dxA = xs2 - nx4.xy;
            const v2f dxB = xs2 - nx4.zw;
            const v2f dyA = ys2 - ny4.xy;
            const v2f dyB = ys2 - ny4.zw;
            // eps folded into the fma chain: r2 >= 2^-40, no low clamp op
            const v2f r2A = __builtin_elementwise_fma(
                dyA, dyA, __builtin_elementwise_fma(dxA, dxA, eps2));
            const v2f r2B = __builtin_elementwise_fma(
                dyB, dyB, __builtin_elementwise_fma(dxB, dxB, eps2));
            const float r2k[4] = { r2A.x, r2A.y, r2B.x, r2B.y };
            #pragma unroll
            for (int k = 0; k < 4; ++k) {
                // no clamps: real r2 <= ~250, sentinel <= ~740, table to 1024
                const unsigned raw =
                    (__builtin_bit_cast(unsigned, r2k[k]) >> 16) & 0xFFF8u;
                const float2 cs = *(const float2*)(tb + raw);  // ds_read_b64
                accC += cs.x;
                accS = fmaf(cs.y, r2k[k], accS);
            }
        }
    }

    // Combine the 4 wave-partials of each element via LDS.
    const float av = accC + accS;
    if (w != 0) smem[L_PART + (w - 1) * EPB + lane] = av;
    __syncthreads();
    if (w == 0 && e < B) {
        out[e] = av + smem[L_PART + lane]
                    + smem[L_PART + EPB + lane]
                    + smem[L_PART + 2 * EPB + lane];   // coalesced store
    }
}

extern "C" void kernel_launch(void* const* d_in, const int* in_sizes, int n_in,
                              void* d_out, int out_size, void* d_ws, size_t ws_size,
                              hipStream_t stream) {
    const float* x   = (const float*)d_in[0];
    const float* nbr = (const float*)d_in[1];
    const float* msk = (const float*)d_in[2];
    float* out = (float*)d_out;

    const int B = in_sizes[0] / 24;

    init_kernel<<<1, BLOCK, 0, stream>>>(nbr, msk);

    const int blocks = (B + EPB - 1) / EPB;
    pot_energy_kernel<<<blocks, BLOCK, 0, stream>>>(x, out, B);
}